// Round 6
// baseline (917.678 us; speedup 1.0000x reference)
//
#include <hip/hip_runtime.h>
#include <math.h>

#define N_TOK 8192
#define HID   8192
#define NG    16
#define NE    16
#define NSL   8                 // split-K slices
#define KSL   (HID / NSL)       // 1024 k per slice
#define TKB   32                // tokens per block (4 waves x 8) + bucket tile size

// ---- ws layout (bytes) ----
#define OFF_CNT   0u
#define OFF_GSUM  64u
#define OFF_ESUM  128u
#define OFF_NTIL  192u
#define ZERO_BYTES 256u
#define OFF_BUCK  256u                                   // int[16][8192] = 512 KB
#define OFF_SCHED (OFF_BUCK + NG*N_TOK*4)                // int[2048]
#define OFF_GIDX  (OFF_SCHED + 2048*4)                   // int[8192]
#define OFF_MGT   (OFF_GIDX + N_TOK*4)                   // float[16][16][8192] = 16 MiB
#define OFF_PART  (OFF_MGT + 16777216u)                  // float[8][8192][16] = 4 MiB (reused by both tiers)

// global -> LDS DMA, 16B per lane; LDS dest = wave-uniform base + lane*16
__device__ __forceinline__ void glds16(const float* gp, float* lp) {
    __builtin_amdgcn_global_load_lds(
        (const __attribute__((address_space(1))) void*)gp,
        (__attribute__((address_space(3))) void*)lp, 16, 0, 0);
}

// cross-lane fp32 reduce-scatter on 64 accs: after rounds 32..1,
// lane L holds original acc index L.  (R0-harness-verified mapping)
#define RS_ROUND(o, half)                                                 \
  {                                                                       \
    const bool hi_ = (lane & (o)) != 0;                                   \
    _Pragma("unroll")                                                     \
    for (int i_ = 0; i_ < (half); ++i_) {                                 \
      float s_ = hi_ ? acc[i_] : acc[i_ + (half)];                        \
      float r_ = __shfl_xor(s_, (o));                                     \
      acc[i_] = (hi_ ? acc[i_ + (half)] : acc[i_]) + r_;                  \
    }                                                                     \
  }

// ---------------- Tier-1 GEMM: partial group logits (split-K, barrier-free) ----------------
// Block = (token-block tb, k-slice s). Weights [16][1024] resident in LDS for the
// whole kernel (loaded once). Token loop has NO barriers: per wave, batches of
// 4 tokens x 1024 k with all hidden loads issued up front (counted waits only).
__global__ __launch_bounds__(256, 2) void k_group(
    const float* __restrict__ hid, const float* __restrict__ gw,
    float* __restrict__ pg)
{
    __shared__ float Wl[NG * KSL];                   // 64 KB, resident
    const int tid  = threadIdx.x;
    const int lane = tid & 63;
    const int wv   = tid >> 6;                       // 0..3
    const int s    = blockIdx.x & 7;
    const int tb0  = (blockIdx.x >> 3) * TKB;
    const int ks   = s * KSL;

    #pragma unroll
    for (int j = 0; j < 16; ++j) {                   // one-time weight DMA: 64 x 1KB
        int m = wv * 16 + j;                         // m = g*4 + q
        glds16(gw + (size_t)(m >> 2) * HID + ks + (m & 3) * 256 + 4 * lane,
               &Wl[m * 256]);
    }
    __syncthreads();                                 // the only barrier in the kernel

    const int t0w = tb0 + wv * 8;                    // wave owns 8 tokens
    #pragma unroll 1
    for (int b = 0; b < 2; ++b) {
        const int tb = t0w + b * 4;
        float4 a[4][4];                              // 4 tokens x 4 k-chunks, issued up front
        #pragma unroll
        for (int t = 0; t < 4; ++t) {
            #pragma unroll
            for (int c = 0; c < 4; ++c)
                a[t][c] = *(const float4*)
                    &hid[(size_t)(tb + t) * HID + ks + c * 256 + 4 * lane];
        }
        float acc[64];
        #pragma unroll
        for (int i = 0; i < 64; ++i) acc[i] = 0.f;
        #pragma unroll
        for (int c = 0; c < 4; ++c) {
            #pragma unroll
            for (int g = 0; g < NG; ++g) {
                float4 w = *(const float4*)&Wl[(g * 4 + c) * 256 + 4 * lane];
                #pragma unroll
                for (int t = 0; t < 4; ++t) {
                    acc[t*16+g] = fmaf(a[t][c].x, w.x, acc[t*16+g]);
                    acc[t*16+g] = fmaf(a[t][c].y, w.y, acc[t*16+g]);
                    acc[t*16+g] = fmaf(a[t][c].z, w.z, acc[t*16+g]);
                    acc[t*16+g] = fmaf(a[t][c].w, w.w, acc[t*16+g]);
                }
            }
        }
        RS_ROUND(32, 32) RS_ROUND(16, 16) RS_ROUND(8, 8)
        RS_ROUND(4, 4)   RS_ROUND(2, 2)   RS_ROUND(1, 1)
        // lane holds partial logit for (t = tb + (lane>>4), g = lane&15)
        pg[((size_t)s * N_TOK + tb + (lane >> 4)) * 16 + (lane & 15)] = acc[0];
    }
}

// ---------------- Tier-1 finalize: sum slices + softmax/argmax/bucket ----------------
__global__ __launch_bounds__(256) void k_gfin(
    const float* __restrict__ pg, int* __restrict__ cnt, int* __restrict__ buckets,
    float* __restrict__ gsum, int* __restrict__ gidx)
{
    const int t    = blockIdx.x * 256 + threadIdx.x;
    const int lane = threadIdx.x & 63;
    float l[16];
    #pragma unroll
    for (int q = 0; q < 4; ++q) {
        float4 v = *(const float4*)&pg[(size_t)t * 16 + 4 * q];
        l[4*q+0] = v.x; l[4*q+1] = v.y; l[4*q+2] = v.z; l[4*q+3] = v.w;
    }
    #pragma unroll
    for (int s2 = 1; s2 < NSL; ++s2) {
        #pragma unroll
        for (int q = 0; q < 4; ++q) {
            float4 v = *(const float4*)&pg[((size_t)s2 * N_TOK + t) * 16 + 4 * q];
            l[4*q+0] += v.x; l[4*q+1] += v.y; l[4*q+2] += v.z; l[4*q+3] += v.w;
        }
    }
    float mx = l[0];
    #pragma unroll
    for (int g = 1; g < NG; ++g) mx = fmaxf(mx, l[g]);
    float p[16], sum = 0.f;
    #pragma unroll
    for (int g = 0; g < NG; ++g) { p[g] = expf(l[g] - mx); sum += p[g]; }
    float inv = 1.f / sum;
    #pragma unroll
    for (int g = 0; g < NG; ++g) p[g] *= inv;
    #pragma unroll
    for (int g = 0; g < NG; ++g) {                   // gsum: wave-reduce then 1 atomic
        float v = p[g];
        #pragma unroll
        for (int o = 32; o; o >>= 1) v += __shfl_xor(v, o);
        if (lane == 0) unsafeAtomicAdd(&gsum[g], v);
    }
    int gi = 0; float bv = l[0];                     // first-index-wins argmax
    #pragma unroll
    for (int g = 1; g < NG; ++g) if (l[g] > bv) { bv = l[g]; gi = g; }
    gidx[t] = gi;
    int pos = atomicAdd(&cnt[gi], 1);
    buckets[gi * N_TOK + pos] = t;
}

// ---------------- mg [g][k][e] -> mgT [g][e][k] ----------------
__global__ __launch_bounds__(256) void k_tr(
    const float* __restrict__ mg, float* __restrict__ mgT)
{
    const int g  = blockIdx.x >> 7;
    const int kb = (blockIdx.x & 127) * 64;
    const int e  = threadIdx.x & 15;
    const int kq = threadIdx.x >> 4;
    const int k0 = kb + 4 * kq;
    const float* src = mg + (size_t)g * HID * NE;
    float4 v;
    v.x = src[(size_t)(k0 + 0) * NE + e];
    v.y = src[(size_t)(k0 + 1) * NE + e];
    v.z = src[(size_t)(k0 + 2) * NE + e];
    v.w = src[(size_t)(k0 + 3) * NE + e];
    *(float4*)&mgT[(size_t)(g * NE + e) * HID + k0] = v;
}

// ---------------- build compact (group,tile) worklist, tile = 32 tokens ----------------
__global__ void k_sched(const int* __restrict__ cnt, int* __restrict__ sched,
                        int* __restrict__ ntile)
{
    __shared__ int pref[NG + 1];
    if (threadIdx.x == 0) {
        int s = 0;
        for (int g = 0; g < NG; ++g) { pref[g] = s; s += (cnt[g] + TKB - 1) / TKB; }
        pref[NG] = s; *ntile = s;
    }
    __syncthreads();
    int total = pref[NG];
    for (int i = threadIdx.x; i < total; i += blockDim.x) {
        int g = 0;
        while (g < NG - 1 && i >= pref[g + 1]) ++g;
        sched[i] = (g << 16) | (i - pref[g]);
    }
}

// ---------------- Tier-2 GEMM: partial mini logits (same barrier-free engine) ----------------
__global__ __launch_bounds__(256, 2) void k_mini(
    const float* __restrict__ hid, const float* __restrict__ mgT,
    const int* __restrict__ cnt, const int* __restrict__ buckets,
    const int* __restrict__ sched, const int* __restrict__ ntile,
    float* __restrict__ pm)
{
    const int widx = blockIdx.x >> 3;
    if (widx >= *ntile) return;
    const int s    = blockIdx.x & 7;
    const int enc  = sched[widx];
    const int g    = enc >> 16;
    const int tile = enc & 0xffff;
    const int n    = cnt[g] - tile * TKB;            // >=1; >TKB for non-final tiles

    __shared__ float Wl[NE * KSL];                   // 64 KB, resident
    __shared__ int   rows[TKB];
    const int tid  = threadIdx.x;
    const int lane = tid & 63;
    const int wv   = tid >> 6;
    const int ks   = s * KSL;
    const float* __restrict__ wg = mgT + (size_t)g * NE * HID;

    #pragma unroll
    for (int j = 0; j < 16; ++j) {
        int m = wv * 16 + j;                         // m = e*4 + q
        glds16(wg + (size_t)(m >> 2) * HID + ks + (m & 3) * 256 + 4 * lane,
               &Wl[m * 256]);
    }
    if (tid < TKB) {
        int idx = tid < n ? tid : (n - 1);           // clamp dup tail (dup rows write
        rows[tid] = buckets[g * N_TOK + tile * TKB + idx];   // identical pm values)
    }
    __syncthreads();                                 // only barrier (weights + rows)

    #pragma unroll 1
    for (int b = 0; b < 2; ++b) {
        const int rbase = wv * 8 + b * 4;
        float4 a[4][4];
        #pragma unroll
        for (int t = 0; t < 4; ++t) {
            const float* at = hid + (size_t)rows[rbase + t] * HID + ks;
            #pragma unroll
            for (int c = 0; c < 4; ++c)
                a[t][c] = *(const float4*)&at[c * 256 + 4 * lane];
        }
        float acc[64];
        #pragma unroll
        for (int i = 0; i < 64; ++i) acc[i] = 0.f;
        #pragma unroll
        for (int c = 0; c < 4; ++c) {
            #pragma unroll
            for (int e = 0; e < NE; ++e) {
                float4 w = *(const float4*)&Wl[(e * 4 + c) * 256 + 4 * lane];
                #pragma unroll
                for (int t = 0; t < 4; ++t) {
                    acc[t*16+e] = fmaf(a[t][c].x, w.x, acc[t*16+e]);
                    acc[t*16+e] = fmaf(a[t][c].y, w.y, acc[t*16+e]);
                    acc[t*16+e] = fmaf(a[t][c].z, w.z, acc[t*16+e]);
                    acc[t*16+e] = fmaf(a[t][c].w, w.w, acc[t*16+e]);
                }
            }
        }
        RS_ROUND(32, 32) RS_ROUND(16, 16) RS_ROUND(8, 8)
        RS_ROUND(4, 4)   RS_ROUND(2, 2)   RS_ROUND(1, 1)
        // dup-clamped rows store identical values -> benign overlap
        pm[((size_t)s * N_TOK + rows[rbase + (lane >> 4)]) * 16 + (lane & 15)] = acc[0];
    }
}

// ---------------- Tier-2 finalize: sum slices + softmax/top-4/output ----------------
__global__ __launch_bounds__(256) void k_mfin(
    const float* __restrict__ pm, const int* __restrict__ gidx,
    float* __restrict__ out, float* __restrict__ esum)
{
    const int t    = blockIdx.x * 256 + threadIdx.x;
    const int lane = threadIdx.x & 63;
    float l[16];
    #pragma unroll
    for (int q = 0; q < 4; ++q) {
        float4 v = *(const float4*)&pm[(size_t)t * 16 + 4 * q];
        l[4*q+0] = v.x; l[4*q+1] = v.y; l[4*q+2] = v.z; l[4*q+3] = v.w;
    }
    #pragma unroll
    for (int s2 = 1; s2 < NSL; ++s2) {
        #pragma unroll
        for (int q = 0; q < 4; ++q) {
            float4 v = *(const float4*)&pm[((size_t)s2 * N_TOK + t) * 16 + 4 * q];
            l[4*q+0] += v.x; l[4*q+1] += v.y; l[4*q+2] += v.z; l[4*q+3] += v.w;
        }
    }
    float mx = l[0];
    #pragma unroll
    for (int e = 1; e < NE; ++e) mx = fmaxf(mx, l[e]);
    float p[16], sum = 0.f;
    #pragma unroll
    for (int e = 0; e < NE; ++e) { p[e] = expf(l[e] - mx); sum += p[e]; }
    float inv = 1.f / sum;
    #pragma unroll
    for (int e = 0; e < NE; ++e) p[e] *= inv;
    #pragma unroll
    for (int e = 0; e < NE; ++e) {                   // esum: wave-reduce then 1 atomic
        float v = p[e];
        #pragma unroll
        for (int o = 32; o; o >>= 1) v += __shfl_xor(v, o);
        if (lane == 0) unsafeAtomicAdd(&esum[e], v);
    }
    const int g = gidx[t];
    unsigned used = 0;
    float tv[4]; int ti[4];
    #pragma unroll
    for (int j = 0; j < 4; ++j) {                    // first-index-wins top-4
        float best = -1.f; int bi = 0;
        #pragma unroll
        for (int e = 0; e < NE; ++e)
            if (!((used >> e) & 1u) && p[e] > best) { best = p[e]; bi = e; }
        used |= 1u << bi; tv[j] = best; ti[j] = bi;
    }
    float inv4 = 1.f / (tv[0] + tv[1] + tv[2] + tv[3]);   // group prob cancels
    #pragma unroll
    for (int j = 0; j < 4; ++j) {
        out[t * 4 + j]             = tv[j] * inv4;
        out[N_TOK * 4 + t * 4 + j] = (float)(g * NE + ti[j]);
    }
}

// ---------------- aux loss scalar ----------------
__global__ void k_aux(const float* __restrict__ gsum, const float* __restrict__ esum,
                      float* __restrict__ out)
{
    if (threadIdx.x == 0) {
        float a = 0.f;
        for (int g = 0; g < NG; ++g) { float m = gsum[g] * (1.f / N_TOK); a += m * m; }
        for (int e = 0; e < NE; ++e) { float m = esum[e] * (1.f / N_TOK); a += m * m; }
        out[N_TOK * 8] = a;   // element 65536
    }
}

extern "C" void kernel_launch(void* const* d_in, const int* in_sizes, int n_in,
                              void* d_out, int out_size, void* d_ws, size_t ws_size,
                              hipStream_t stream) {
    const float* hid = (const float*)d_in[0];   // [8192,8192]
    const float* gw  = (const float*)d_in[1];   // [16,8192]
    const float* mg  = (const float*)d_in[2];   // [16,8192,16]
    float* out = (float*)d_out;
    char*  ws  = (char*)d_ws;
    int*    cnt     = (int*)   (ws + OFF_CNT);
    float*  gsum    = (float*) (ws + OFF_GSUM);
    float*  esum    = (float*) (ws + OFF_ESUM);
    int*    ntile   = (int*)   (ws + OFF_NTIL);
    int*    buckets = (int*)   (ws + OFF_BUCK);
    int*    sched   = (int*)   (ws + OFF_SCHED);
    int*    gidx    = (int*)   (ws + OFF_GIDX);
    float*  mgT     = (float*) (ws + OFF_MGT);
    float*  part    = (float*) (ws + OFF_PART);  // reused: pgrp then pmini

    hipMemsetAsync(d_ws, 0, ZERO_BYTES, stream);

    k_tr   <<<2048, 256, 0, stream>>>(mg, mgT);
    k_group<<<(N_TOK / TKB) * NSL, 256, 0, stream>>>(hid, gw, part);
    k_gfin <<<N_TOK / 256, 256, 0, stream>>>(part, cnt, buckets, gsum, gidx);
    k_sched<<<1, 256, 0, stream>>>(cnt, sched, ntile);
    k_mini <<<(N_TOK / TKB + NG) * NSL, 256, 0, stream>>>(hid, mgT, cnt, buckets,
                                                          sched, ntile, part);
    k_mfin <<<N_TOK / 256, 256, 0, stream>>>(part, gidx, out, esum);
    k_aux  <<<1, 64, 0, stream>>>(gsum, esum, out);
}

// Round 7
// 772.216 us; speedup vs baseline: 1.1884x; 1.1884x over previous
//
#include <hip/hip_runtime.h>
#include <math.h>

#define N_TOK 8192
#define HID   8192
#define NG    16
#define NE    16
#define NSL   16                // split-K slices
#define KSL   (HID / NSL)       // 512 k per slice
#define TKB   32                // tokens per block (4 waves x 8); bucket tile size

// ---- ws layout (bytes) ----
#define OFF_CNT   0u
#define OFF_GSUM  64u
#define OFF_ESUM  128u
#define OFF_NTIL  192u
#define ZERO_BYTES 256u
#define OFF_BUCK  256u                                   // int[16][8192] = 512 KB
#define OFF_SCHED (OFF_BUCK + NG*N_TOK*4)                // int[2048]
#define OFF_GIDX  (OFF_SCHED + 2048*4)                   // int[8192]
#define OFF_MGT   (OFF_GIDX + N_TOK*4)                   // float[16][16][8192] = 16 MiB
#define OFF_PART  (OFF_MGT + 16777216u)                  // float[16][8192][16] = 8 MiB

// global -> LDS DMA, 16B per lane; LDS dest = wave-uniform base + lane*16
__device__ __forceinline__ void glds16(const float* gp, float* lp) {
    __builtin_amdgcn_global_load_lds(
        (const __attribute__((address_space(1))) void*)gp,
        (__attribute__((address_space(3))) void*)lp, 16, 0, 0);
}

// cross-lane fp32 reduce-scatter on 64 accs: after rounds 32..1,
// lane L holds original acc index L.  (harness-verified mapping)
#define RS_ROUND(o, half)                                                 \
  {                                                                       \
    const bool hi_ = (lane & (o)) != 0;                                   \
    _Pragma("unroll")                                                     \
    for (int i_ = 0; i_ < (half); ++i_) {                                 \
      float s_ = hi_ ? acc[i_] : acc[i_ + (half)];                        \
      float r_ = __shfl_xor(s_, (o));                                     \
      acc[i_] = (hi_ ? acc[i_ + (half)] : acc[i_]) + r_;                  \
    }                                                                     \
  }
#define RS_ALL RS_ROUND(32,32) RS_ROUND(16,16) RS_ROUND(8,8) \
               RS_ROUND(4,4)   RS_ROUND(2,2)   RS_ROUND(1,1)

// FMA sub-step: 4 tokens x 16 rows x one 256-float chunk (c = M0).
// INIT variant starts acc with a MUL (no 64-wide zero-fill pass).
#define CSTEP(BUF, M0)                                                    \
  _Pragma("unroll")                                                       \
  for (int g_ = 0; g_ < 16; ++g_) {                                       \
    float4 w_ = *(const float4*)&Wl[((g_ << 1) + (M0)) * 256 + 4 * lane]; \
    _Pragma("unroll")                                                     \
    for (int t_ = 0; t_ < 4; ++t_) {                                      \
      acc[t_*16+g_] = fmaf(BUF[t_].x, w_.x, acc[t_*16+g_]);               \
      acc[t_*16+g_] = fmaf(BUF[t_].y, w_.y, acc[t_*16+g_]);               \
      acc[t_*16+g_] = fmaf(BUF[t_].z, w_.z, acc[t_*16+g_]);               \
      acc[t_*16+g_] = fmaf(BUF[t_].w, w_.w, acc[t_*16+g_]);               \
    }                                                                     \
  }
#define CSTEP_INIT(BUF, M0)                                               \
  _Pragma("unroll")                                                       \
  for (int g_ = 0; g_ < 16; ++g_) {                                       \
    float4 w_ = *(const float4*)&Wl[((g_ << 1) + (M0)) * 256 + 4 * lane]; \
    _Pragma("unroll")                                                     \
    for (int t_ = 0; t_ < 4; ++t_) {                                      \
      acc[t_*16+g_] = BUF[t_].x * w_.x;                                   \
      acc[t_*16+g_] = fmaf(BUF[t_].y, w_.y, acc[t_*16+g_]);               \
      acc[t_*16+g_] = fmaf(BUF[t_].z, w_.z, acc[t_*16+g_]);               \
      acc[t_*16+g_] = fmaf(BUF[t_].w, w_.w, acc[t_*16+g_]);               \
    }                                                                     \
  }

// ---------------- Tier-1 GEMM: partial group logits (split-K, barrier-free) ----------------
// Block = (32-token tile, k-slice). Weights [16][512] LDS-resident (one DMA +
// one barrier). Per wave: 2 groups of 4 tokens; per group 2 pipelined sub-steps
// (cur/nxt 256-float chunks). Peak VGPR ~110: acc[64]+cur[16]+nxt[16]+addr.
__global__ __launch_bounds__(256, 2) void k_group(
    const float* __restrict__ hid, const float* __restrict__ gw,
    float* __restrict__ pg)
{
    __shared__ float Wl[NG * KSL];                   // 32 KB, resident
    const int tid  = threadIdx.x;
    const int lane = tid & 63;
    const int wv   = tid >> 6;                       // 0..3
    const int s    = blockIdx.x & (NSL - 1);
    const int tb0  = (blockIdx.x >> 4) * TKB;
    const int ks   = s * KSL;

    #pragma unroll
    for (int j = 0; j < 8; ++j) {                    // one-time weight DMA: 32 x 1KB
        int m = wv * 8 + j;                          // m = g*2 + c
        glds16(gw + (size_t)(m >> 1) * HID + ks + (m & 1) * 256 + 4 * lane,
               &Wl[m * 256]);
    }
    __syncthreads();                                 // the only barrier

    const float* __restrict__ a0 = hid + (size_t)(tb0 + wv * 8) * HID + ks + 4 * lane;
    float4 cur[4], nxt[4];
    float acc[64];

    #pragma unroll
    for (int t = 0; t < 4; ++t) cur[t] = *(const float4*)&a0[(size_t)t * HID];

    // ---- group 0 (tokens 0..3) ----
    #pragma unroll
    for (int t = 0; t < 4; ++t) nxt[t] = *(const float4*)&a0[(size_t)t * HID + 256];
    CSTEP_INIT(cur, 0)
    #pragma unroll
    for (int t = 0; t < 4; ++t) cur[t] = *(const float4*)&a0[(size_t)(4 + t) * HID];
    CSTEP(nxt, 1)
    RS_ALL
    pg[((size_t)s * N_TOK + tb0 + wv * 8 + (lane >> 4)) * 16 + (lane & 15)] = acc[0];

    // ---- group 1 (tokens 4..7) ----
    #pragma unroll
    for (int t = 0; t < 4; ++t) nxt[t] = *(const float4*)&a0[(size_t)(4 + t) * HID + 256];
    CSTEP_INIT(cur, 0)
    CSTEP(nxt, 1)
    RS_ALL
    pg[((size_t)s * N_TOK + tb0 + wv * 8 + 4 + (lane >> 4)) * 16 + (lane & 15)] = acc[0];
}

// ---------------- Tier-1 finalize: sum slices + softmax/argmax/bucket ----------------
__global__ __launch_bounds__(256) void k_gfin(
    const float* __restrict__ pg, int* __restrict__ cnt, int* __restrict__ buckets,
    float* __restrict__ gsum, int* __restrict__ gidx)
{
    const int t    = blockIdx.x * 256 + threadIdx.x;
    const int lane = threadIdx.x & 63;
    float l[16];
    #pragma unroll
    for (int q = 0; q < 4; ++q) {
        float4 v = *(const float4*)&pg[(size_t)t * 16 + 4 * q];
        l[4*q+0] = v.x; l[4*q+1] = v.y; l[4*q+2] = v.z; l[4*q+3] = v.w;
    }
    for (int s2 = 1; s2 < NSL; ++s2) {
        #pragma unroll
        for (int q = 0; q < 4; ++q) {
            float4 v = *(const float4*)&pg[((size_t)s2 * N_TOK + t) * 16 + 4 * q];
            l[4*q+0] += v.x; l[4*q+1] += v.y; l[4*q+2] += v.z; l[4*q+3] += v.w;
        }
    }
    float mx = l[0];
    #pragma unroll
    for (int g = 1; g < NG; ++g) mx = fmaxf(mx, l[g]);
    float p[16], sum = 0.f;
    #pragma unroll
    for (int g = 0; g < NG; ++g) { p[g] = expf(l[g] - mx); sum += p[g]; }
    float inv = 1.f / sum;
    #pragma unroll
    for (int g = 0; g < NG; ++g) p[g] *= inv;
    #pragma unroll
    for (int g = 0; g < NG; ++g) {                   // gsum: wave-reduce then 1 atomic
        float v = p[g];
        #pragma unroll
        for (int o = 32; o; o >>= 1) v += __shfl_xor(v, o);
        if (lane == 0) unsafeAtomicAdd(&gsum[g], v);
    }
    int gi = 0; float bv = l[0];                     // first-index-wins argmax
    #pragma unroll
    for (int g = 1; g < NG; ++g) if (l[g] > bv) { bv = l[g]; gi = g; }
    gidx[t] = gi;
    int pos = atomicAdd(&cnt[gi], 1);
    buckets[gi * N_TOK + pos] = t;
}

// ---------------- mg [g][k][e] -> mgT [g][e][k] ----------------
__global__ __launch_bounds__(256) void k_tr(
    const float* __restrict__ mg, float* __restrict__ mgT)
{
    const int g  = blockIdx.x >> 7;
    const int kb = (blockIdx.x & 127) * 64;
    const int e  = threadIdx.x & 15;
    const int kq = threadIdx.x >> 4;
    const int k0 = kb + 4 * kq;
    const float* src = mg + (size_t)g * HID * NE;
    float4 v;
    v.x = src[(size_t)(k0 + 0) * NE + e];
    v.y = src[(size_t)(k0 + 1) * NE + e];
    v.z = src[(size_t)(k0 + 2) * NE + e];
    v.w = src[(size_t)(k0 + 3) * NE + e];
    *(float4*)&mgT[(size_t)(g * NE + e) * HID + k0] = v;
}

// ---------------- build compact (group,tile) worklist, tile = 32 tokens ----------------
__global__ void k_sched(const int* __restrict__ cnt, int* __restrict__ sched,
                        int* __restrict__ ntile)
{
    __shared__ int pref[NG + 1];
    if (threadIdx.x == 0) {
        int s = 0;
        for (int g = 0; g < NG; ++g) { pref[g] = s; s += (cnt[g] + TKB - 1) / TKB; }
        pref[NG] = s; *ntile = s;
    }
    __syncthreads();
    int total = pref[NG];
    for (int i = threadIdx.x; i < total; i += blockDim.x) {
        int g = 0;
        while (g < NG - 1 && i >= pref[g + 1]) ++g;
        sched[i] = (g << 16) | (i - pref[g]);
    }
}

// ---------------- Tier-2 GEMM: partial mini logits (same engine, bucketed rows) ----------------
__global__ __launch_bounds__(256, 2) void k_mini(
    const float* __restrict__ hid, const float* __restrict__ mgT,
    const int* __restrict__ cnt, const int* __restrict__ buckets,
    const int* __restrict__ sched, const int* __restrict__ ntile,
    float* __restrict__ pm)
{
    const int widx = blockIdx.x >> 4;
    if (widx >= *ntile) return;
    const int s    = blockIdx.x & (NSL - 1);
    const int enc  = sched[widx];
    const int g    = enc >> 16;
    const int tile = enc & 0xffff;
    const int n    = cnt[g] - tile * TKB;            // valid tokens in this tile

    __shared__ float Wl[NE * KSL];                   // 32 KB, resident
    __shared__ int   rows[TKB];
    const int tid  = threadIdx.x;
    const int lane = tid & 63;
    const int wv   = tid >> 6;
    const int ks   = s * KSL;
    const float* __restrict__ wg = mgT + (size_t)g * NE * HID;

    #pragma unroll
    for (int j = 0; j < 8; ++j) {
        int m = wv * 8 + j;                          // m = e*2 + c
        glds16(wg + (size_t)(m >> 1) * HID + ks + (m & 1) * 256 + 4 * lane,
               &Wl[m * 256]);
    }
    if (tid < TKB) {
        int idx = tid < n ? tid : (n - 1);           // clamp dup tail (dup rows write
        rows[tid] = buckets[g * N_TOK + tile * TKB + idx];   // identical pm values)
    }
    __syncthreads();                                 // only barrier (weights + rows)

    const int rb = wv * 8;
    int rr[8];                                       // static-index only (rule 20)
    #pragma unroll
    for (int j = 0; j < 8; ++j) rr[j] = rows[rb + j];

    float4 cur[4], nxt[4];
    float acc[64];

    #pragma unroll
    for (int t = 0; t < 4; ++t)
        cur[t] = *(const float4*)&hid[(size_t)rr[t] * HID + ks + 4 * lane];

    // ---- group 0 ----
    #pragma unroll
    for (int t = 0; t < 4; ++t)
        nxt[t] = *(const float4*)&hid[(size_t)rr[t] * HID + ks + 256 + 4 * lane];
    CSTEP_INIT(cur, 0)
    #pragma unroll
    for (int t = 0; t < 4; ++t)
        cur[t] = *(const float4*)&hid[(size_t)rr[4 + t] * HID + ks + 4 * lane];
    CSTEP(nxt, 1)
    RS_ALL
    pm[((size_t)s * N_TOK + rows[rb + (lane >> 4)]) * 16 + (lane & 15)] = acc[0];

    // ---- group 1 ----
    #pragma unroll
    for (int t = 0; t < 4; ++t)
        nxt[t] = *(const float4*)&hid[(size_t)rr[4 + t] * HID + ks + 256 + 4 * lane];
    CSTEP_INIT(cur, 0)
    CSTEP(nxt, 1)
    RS_ALL
    pm[((size_t)s * N_TOK + rows[rb + 4 + (lane >> 4)]) * 16 + (lane & 15)] = acc[0];
}

// ---------------- Tier-2 finalize: sum slices + softmax/top-4/output ----------------
__global__ __launch_bounds__(256) void k_mfin(
    const float* __restrict__ pm, const int* __restrict__ gidx,
    float* __restrict__ out, float* __restrict__ esum)
{
    const int t    = blockIdx.x * 256 + threadIdx.x;
    const int lane = threadIdx.x & 63;
    float l[16];
    #pragma unroll
    for (int q = 0; q < 4; ++q) {
        float4 v = *(const float4*)&pm[(size_t)t * 16 + 4 * q];
        l[4*q+0] = v.x; l[4*q+1] = v.y; l[4*q+2] = v.z; l[4*q+3] = v.w;
    }
    for (int s2 = 1; s2 < NSL; ++s2) {
        #pragma unroll
        for (int q = 0; q < 4; ++q) {
            float4 v = *(const float4*)&pm[((size_t)s2 * N_TOK + t) * 16 + 4 * q];
            l[4*q+0] += v.x; l[4*q+1] += v.y; l[4*q+2] += v.z; l[4*q+3] += v.w;
        }
    }
    float mx = l[0];
    #pragma unroll
    for (int e = 1; e < NE; ++e) mx = fmaxf(mx, l[e]);
    float p[16], sum = 0.f;
    #pragma unroll
    for (int e = 0; e < NE; ++e) { p[e] = expf(l[e] - mx); sum += p[e]; }
    float inv = 1.f / sum;
    #pragma unroll
    for (int e = 0; e < NE; ++e) p[e] *= inv;
    #pragma unroll
    for (int e = 0; e < NE; ++e) {                   // esum: wave-reduce then 1 atomic
        float v = p[e];
        #pragma unroll
        for (int o = 32; o; o >>= 1) v += __shfl_xor(v, o);
        if (lane == 0) unsafeAtomicAdd(&esum[e], v);
    }
    const int g = gidx[t];
    unsigned used = 0;
    float tv[4]; int ti[4];
    #pragma unroll
    for (int j = 0; j < 4; ++j) {                    // first-index-wins top-4
        float best = -1.f; int bi = 0;
        #pragma unroll
        for (int e = 0; e < NE; ++e)
            if (!((used >> e) & 1u) && p[e] > best) { best = p[e]; bi = e; }
        used |= 1u << bi; tv[j] = best; ti[j] = bi;
    }
    float inv4 = 1.f / (tv[0] + tv[1] + tv[2] + tv[3]);   // group prob cancels
    #pragma unroll
    for (int j = 0; j < 4; ++j) {
        out[t * 4 + j]             = tv[j] * inv4;
        out[N_TOK * 4 + t * 4 + j] = (float)(g * NE + ti[j]);
    }
}

// ---------------- aux loss scalar ----------------
__global__ void k_aux(const float* __restrict__ gsum, const float* __restrict__ esum,
                      float* __restrict__ out)
{
    if (threadIdx.x == 0) {
        float a = 0.f;
        for (int g = 0; g < NG; ++g) { float m = gsum[g] * (1.f / N_TOK); a += m * m; }
        for (int e = 0; e < NE; ++e) { float m = esum[e] * (1.f / N_TOK); a += m * m; }
        out[N_TOK * 8] = a;   // element 65536
    }
}

extern "C" void kernel_launch(void* const* d_in, const int* in_sizes, int n_in,
                              void* d_out, int out_size, void* d_ws, size_t ws_size,
                              hipStream_t stream) {
    const float* hid = (const float*)d_in[0];   // [8192,8192]
    const float* gw  = (const float*)d_in[1];   // [16,8192]
    const float* mg  = (const float*)d_in[2];   // [16,8192,16]
    float* out = (float*)d_out;
    char*  ws  = (char*)d_ws;
    int*    cnt     = (int*)   (ws + OFF_CNT);
    float*  gsum    = (float*) (ws + OFF_GSUM);
    float*  esum    = (float*) (ws + OFF_ESUM);
    int*    ntile   = (int*)   (ws + OFF_NTIL);
    int*    buckets = (int*)   (ws + OFF_BUCK);
    int*    sched   = (int*)   (ws + OFF_SCHED);
    int*    gidx    = (int*)   (ws + OFF_GIDX);
    float*  mgT     = (float*) (ws + OFF_MGT);
    float*  part    = (float*) (ws + OFF_PART);  // reused: pgrp then pmini

    hipMemsetAsync(d_ws, 0, ZERO_BYTES, stream);

    k_tr   <<<2048, 256, 0, stream>>>(mg, mgT);
    k_group<<<(N_TOK / TKB) * NSL, 256, 0, stream>>>(hid, gw, part);
    k_gfin <<<N_TOK / 256, 256, 0, stream>>>(part, cnt, buckets, gsum, gidx);
    k_sched<<<1, 256, 0, stream>>>(cnt, sched, ntile);
    k_mini <<<(N_TOK / TKB + NG) * NSL, 256, 0, stream>>>(hid, mgT, cnt, buckets,
                                                          sched, ntile, part);
    k_mfin <<<N_TOK / 256, 256, 0, stream>>>(part, gidx, out, esum);
    k_aux  <<<1, 64, 0, stream>>>(gsum, esum, out);
}